// Round 7
// baseline (302.818 us; speedup 1.0000x reference)
//
#include <hip/hip_runtime.h>
#include <math.h>

#define TT 512
typedef float f32x2 __attribute__((ext_vector_type(2)));

#define LOG2E 1.4426950408889634f

__device__ __forceinline__ float fast_rcp(float v)  { return __builtin_amdgcn_rcpf(v); }
__device__ __forceinline__ float fast_exp2(float v) { return __builtin_amdgcn_exp2f(v); }

// quad_perm DPP: xor1 = [1,0,3,2] = 0xB1 ; xor2 = [2,3,0,1] = 0x4E
template<int CTRL>
__device__ __forceinline__ float dppq(float v) {
    return __int_as_float(__builtin_amdgcn_update_dpp(
        __float_as_int(v), __float_as_int(v), CTRL, 0xF, 0xF, false));
}

// Hand-emitted packed f32 FMA: d = a*b + c on both 32-bit halves (VOP3P).
// Bit-identical to two scalar fmaf. The "v" constraints force all operands
// into arch VGPR pairs at every use -> RA cannot park weights in AGPRs.
__device__ __forceinline__ f32x2 pk_fma(f32x2 a, f32x2 b, f32x2 c) {
    f32x2 d;
    asm("v_pk_fma_f32 %0, %1, %2, %3" : "=v"(d) : "v"(a), "v"(b), "v"(c));
    return d;
}
#define FMA2(A, B, C) pk_fma((A), (B), (C))

// One wave per batch element. Lane l = 4*j + g (g: 0=i,1=f,2=g,3=o ; j = hidden unit).
// Lane owns weight row g*16+j of W_hh0 / W_ih1 / W_hh1 (24 f32x2 regs).
// h0,h1 broadcast through LDS; cross-gate combines via quad_perm DPP (VALU pipe).
__global__ __launch_bounds__(64, 1)
void lstm2_wave(const float* __restrict__ x,
                const float* __restrict__ W_ih0, const float* __restrict__ W_hh0,
                const float* __restrict__ b_ih0, const float* __restrict__ b_hh0,
                const float* __restrict__ W_ih1, const float* __restrict__ W_hh1,
                const float* __restrict__ b_ih1, const float* __restrict__ b_hh1,
                const float* __restrict__ W_fc,  const float* __restrict__ b_fc,
                float* __restrict__ out)
{
    const int l = threadIdx.x;
    const int g = l & 3;           // gate: 0=i,1=f,2=g,3=o
    const int j = l >> 2;          // hidden unit
    const int b = blockIdx.x;
    const int row = g * 16 + j;    // PyTorch gate-order row

    // ---- per-lane weights: row of each matrix as named f32x2 ----
    f32x2 wa0 = *(const f32x2*)&W_hh0[row * 16 +  0];
    f32x2 wa1 = *(const f32x2*)&W_hh0[row * 16 +  2];
    f32x2 wa2 = *(const f32x2*)&W_hh0[row * 16 +  4];
    f32x2 wa3 = *(const f32x2*)&W_hh0[row * 16 +  6];
    f32x2 wa4 = *(const f32x2*)&W_hh0[row * 16 +  8];
    f32x2 wa5 = *(const f32x2*)&W_hh0[row * 16 + 10];
    f32x2 wa6 = *(const f32x2*)&W_hh0[row * 16 + 12];
    f32x2 wa7 = *(const f32x2*)&W_hh0[row * 16 + 14];
    f32x2 wb0 = *(const f32x2*)&W_ih1[row * 16 +  0];
    f32x2 wb1 = *(const f32x2*)&W_ih1[row * 16 +  2];
    f32x2 wb2 = *(const f32x2*)&W_ih1[row * 16 +  4];
    f32x2 wb3 = *(const f32x2*)&W_ih1[row * 16 +  6];
    f32x2 wb4 = *(const f32x2*)&W_ih1[row * 16 +  8];
    f32x2 wb5 = *(const f32x2*)&W_ih1[row * 16 + 10];
    f32x2 wb6 = *(const f32x2*)&W_ih1[row * 16 + 12];
    f32x2 wb7 = *(const f32x2*)&W_ih1[row * 16 + 14];
    f32x2 wc0 = *(const f32x2*)&W_hh1[row * 16 +  0];
    f32x2 wc1 = *(const f32x2*)&W_hh1[row * 16 +  2];
    f32x2 wc2 = *(const f32x2*)&W_hh1[row * 16 +  4];
    f32x2 wc3 = *(const f32x2*)&W_hh1[row * 16 +  6];
    f32x2 wc4 = *(const f32x2*)&W_hh1[row * 16 +  8];
    f32x2 wc5 = *(const f32x2*)&W_hh1[row * 16 + 10];
    f32x2 wc6 = *(const f32x2*)&W_hh1[row * 16 + 12];
    f32x2 wc7 = *(const f32x2*)&W_hh1[row * 16 + 14];
    const float wx0 = W_ih0[row];                    // D_IN == 1
    const float bb0 = b_ih0[row] + b_hh0[row];
    const float bb1 = b_ih1[row] + b_hh1[row];

    // unified activation constants (per-lane; branchless):
    // sigmoid lanes: 1/(1+2^(-x*log2e)); tanh lane (g==2): 2/(1+2^(-2x*log2e)) - 1
    const bool  isT = (g == 2);
    const bool  isF = (g == 1);
    const float Ca  = isT ? (-2.0f * LOG2E) : (-LOG2E);
    const float Aa  = isT ? 2.0f : 1.0f;
    const float Ba  = isT ? -1.0f : 0.0f;
    const float C2P = 2.0f * LOG2E;

    // hs[0:16)=h0, hs[16:32)=h1, hs[32:64)=trash (all 64 write-addresses distinct)
    __shared__ float hs[64];
    hs[l] = 0.0f;
    const int wslot = (l & 1) ? (((l & 2) << 3) | j) : (32 + (l >> 1));
    float cs0 = 0.0f, cs1 = 0.0f;
    __syncthreads();

    const float* xb = x + (size_t)b * TT;
    float4 xq = *(const float4*)xb;
    const f32x2* h0p = (const f32x2*)&hs[0];
    const f32x2* h1p = (const f32x2*)&hs[16];

#define LSTM_STEP(XI, DO_L1)                                                   \
  {                                                                            \
    const f32x2 p0 = h0p[0], p1 = h0p[1], p2 = h0p[2], p3 = h0p[3];            \
    const f32x2 p4 = h0p[4], p5 = h0p[5], p6 = h0p[6], p7 = h0p[7];            \
    const f32x2 s0 = h1p[0], s1 = h1p[1], s2 = h1p[2], s3 = h1p[3];            \
    const f32x2 s4 = h1p[4], s5 = h1p[5], s6 = h1p[6], s7 = h1p[7];            \
    f32x2 a0 = {fmaf((XI), wx0, bb0), 0.0f};                                   \
    f32x2 a1 = {bb1, 0.0f};                                                    \
    a0 = FMA2(wa0, p0, a0); a1 = FMA2(wb0, p0, a1); a1 = FMA2(wc0, s0, a1);    \
    a0 = FMA2(wa1, p1, a0); a1 = FMA2(wb1, p1, a1); a1 = FMA2(wc1, s1, a1);    \
    a0 = FMA2(wa2, p2, a0); a1 = FMA2(wb2, p2, a1); a1 = FMA2(wc2, s2, a1);    \
    a0 = FMA2(wa3, p3, a0); a1 = FMA2(wb3, p3, a1); a1 = FMA2(wc3, s3, a1);    \
    a0 = FMA2(wa4, p4, a0); a1 = FMA2(wb4, p4, a1); a1 = FMA2(wc4, s4, a1);    \
    a0 = FMA2(wa5, p5, a0); a1 = FMA2(wb5, p5, a1); a1 = FMA2(wc5, s5, a1);    \
    a0 = FMA2(wa6, p6, a0); a1 = FMA2(wb6, p6, a1); a1 = FMA2(wc6, s6, a1);    \
    a0 = FMA2(wa7, p7, a0); a1 = FMA2(wb7, p7, a1); a1 = FMA2(wc7, s7, a1);    \
    const float acc0 = a0.x + a0.y;                                            \
    const float acc1 = a1.x + a1.y;                                            \
    const float act0 = fmaf(Aa, fast_rcp(1.0f + fast_exp2(acc0 * Ca)), Ba);    \
    const float act1 = fmaf(Aa, fast_rcp(1.0f + fast_exp2(acc1 * Ca)), Ba);    \
    const float sw0 = dppq<0x4E>(act0);        /* xor2: i<->g, f<->o */        \
    const float sw1 = dppq<0x4E>(act1);                                        \
    const float xp0 = dppq<0xB1>(act0 * sw0);  /* xor1: f-lane <- i*g */       \
    const float xp1 = dppq<0xB1>(act1 * sw1);                                  \
    const float c0n = fmaf(act0, cs0, xp0);    /* valid on f-lane (act0=f) */  \
    const float c1n = fmaf(sw1, cs1, xp1);     /* valid on o-lane (sw1=f1) */  \
    cs0 = c0n;                                                                 \
    if (DO_L1) cs1 = c1n;                                                      \
    const float tin = isF ? cs0 : cs1;                                         \
    const float e   = fast_exp2(fabsf(tin) * C2P);                             \
    float th = fmaf(-2.0f, fast_rcp(e + 1.0f), 1.0f);                          \
    th = copysignf(th, tin);                                                   \
    const float hv = (isF ? sw0 : act1) * th;  /* o0*tanh(c0) / o1*tanh(c1) */ \
    hs[wslot] = hv;                                                            \
  }

    for (int t0 = 0; t0 < TT; t0 += 4) {
        float4 xn = xq;
        if (t0 + 4 < TT) xn = *(const float4*)(xb + t0 + 4);
        LSTM_STEP(xq.x, (t0 != 0))
        LSTM_STEP(xq.y, true)
        LSTM_STEP(xq.z, true)
        LSTM_STEP(xq.w, true)
        xq = xn;
    }

    // ---- final L1 step: z^{511} from (z^{510}, h0^{511}) ----
    {
        const f32x2 p0 = h0p[0], p1 = h0p[1], p2 = h0p[2], p3 = h0p[3];
        const f32x2 p4 = h0p[4], p5 = h0p[5], p6 = h0p[6], p7 = h0p[7];
        const f32x2 s0 = h1p[0], s1 = h1p[1], s2 = h1p[2], s3 = h1p[3];
        const f32x2 s4 = h1p[4], s5 = h1p[5], s6 = h1p[6], s7 = h1p[7];
        f32x2 a1 = {bb1, 0.0f};
        a1 = FMA2(wb0, p0, a1); a1 = FMA2(wc0, s0, a1);
        a1 = FMA2(wb1, p1, a1); a1 = FMA2(wc1, s1, a1);
        a1 = FMA2(wb2, p2, a1); a1 = FMA2(wc2, s2, a1);
        a1 = FMA2(wb3, p3, a1); a1 = FMA2(wc3, s3, a1);
        a1 = FMA2(wb4, p4, a1); a1 = FMA2(wc4, s4, a1);
        a1 = FMA2(wb5, p5, a1); a1 = FMA2(wc5, s5, a1);
        a1 = FMA2(wb6, p6, a1); a1 = FMA2(wc6, s6, a1);
        a1 = FMA2(wb7, p7, a1); a1 = FMA2(wc7, s7, a1);
        const float acc1 = a1.x + a1.y;
        const float act1 = fmaf(Aa, fast_rcp(1.0f + fast_exp2(acc1 * Ca)), Ba);
        const float sw1 = dppq<0x4E>(act1);
        const float xp1 = dppq<0xB1>(act1 * sw1);
        cs1 = fmaf(sw1, cs1, xp1);                 // valid on o-lane
        const float e = fast_exp2(fabsf(cs1) * C2P);
        float th = fmaf(-2.0f, fast_rcp(e + 1.0f), 1.0f);
        th = copysignf(th, cs1);
        const float h1fin = act1 * th;             // valid on o-lane

        // FC: out[b] = sum_j h1_j * W_fc[j] + b_fc
        const float wfc = W_fc[j];
        float p = (g == 3) ? h1fin * wfc : 0.0f;
        #pragma unroll
        for (int m = 1; m < 64; m <<= 1) p += __shfl_xor(p, m);
        if (l == 0) out[b] = p + b_fc[0];
    }
#undef LSTM_STEP
}

extern "C" void kernel_launch(void* const* d_in, const int* in_sizes, int n_in,
                              void* d_out, int out_size, void* d_ws, size_t ws_size,
                              hipStream_t stream) {
    const float* x     = (const float*)d_in[0];
    const float* W_ih0 = (const float*)d_in[1];
    const float* W_hh0 = (const float*)d_in[2];
    const float* b_ih0 = (const float*)d_in[3];
    const float* b_hh0 = (const float*)d_in[4];
    const float* W_ih1 = (const float*)d_in[5];
    const float* W_hh1 = (const float*)d_in[6];
    const float* b_ih1 = (const float*)d_in[7];
    const float* b_hh1 = (const float*)d_in[8];
    const float* W_fc  = (const float*)d_in[9];
    const float* b_fc  = (const float*)d_in[10];
    float* out = (float*)d_out;

    dim3 grid(4096), block(64);
    hipLaunchKernelGGL(lstm2_wave, grid, block, 0, stream,
                       x, W_ih0, W_hh0, b_ih0, b_hh0,
                       W_ih1, W_hh1, b_ih1, b_hh1, W_fc, b_fc, out);
}

// Round 8
// 278.738 us; speedup vs baseline: 1.0864x; 1.0864x over previous
//
#include <hip/hip_runtime.h>
#include <math.h>

#define TT 512
typedef float f32x2 __attribute__((ext_vector_type(2)));

#define LOG2E 1.4426950408889634f

__device__ __forceinline__ float fast_rcp(float v)  { return __builtin_amdgcn_rcpf(v); }
__device__ __forceinline__ float fast_exp2(float v) { return __builtin_amdgcn_exp2f(v); }

// quad_perm DPP: xor1 = [1,0,3,2] = 0xB1 ; xor2 = [2,3,0,1] = 0x4E
template<int CTRL>
__device__ __forceinline__ float dppq(float v) {
    return __int_as_float(__builtin_amdgcn_update_dpp(
        __float_as_int(v), __float_as_int(v), CTRL, 0xF, 0xF, false));
}
#define FMA2(A, B, C) __builtin_elementwise_fma((A), (B), (C))

// One wave per batch. Lane l = 4*j + g (g: 0=i,1=f,2=g,3=o ; j = hidden unit).
// Inner 508 steps are ONE asm block with explicit registers:
//   v32-63 h state, v64-111 weights (loaded in prologue), v112-127 temps.
// The compiler never allocates the loop -> no AGPR parking / shuttling
// (the failure mode of rounds 1-6: VGPR_Count stuck at 40-44, ~200 instr/step).
__global__ __launch_bounds__(64, 4)
void lstm2_wave(const float* __restrict__ x,
                const float* __restrict__ W_ih0, const float* __restrict__ W_hh0,
                const float* __restrict__ b_ih0, const float* __restrict__ b_hh0,
                const float* __restrict__ W_ih1, const float* __restrict__ W_hh1,
                const float* __restrict__ b_ih1, const float* __restrict__ b_hh1,
                const float* __restrict__ W_fc,  const float* __restrict__ b_fc,
                float* __restrict__ out)
{
    const int l = threadIdx.x;
    const int g = l & 3;           // gate: 0=i,1=f,2=g,3=o
    const int j = l >> 2;          // hidden unit
    const int b = blockIdx.x;
    const int row = g * 16 + j;    // PyTorch gate-order row

    // LDS: floats [0,16) h0 | [16,32) h1 | [32,64) trash | [64,576) x
    __shared__ float lds[576];

    // ---- stage x into LDS (coalesced float4), init h state ----
    const float* xb = x + (size_t)b * TT;
    ((float4*)&lds[64])[l]      = ((const float4*)xb)[l];
    ((float4*)&lds[64])[64 + l] = ((const float4*)xb)[64 + l];
    lds[l] = 0.0f;

    // ---- per-lane weights (C++ copies: used only by peel + epilogue) ----
    const f32x2 wa0 = *(const f32x2*)&W_hh0[row*16+ 0], wa1 = *(const f32x2*)&W_hh0[row*16+ 2];
    const f32x2 wa2 = *(const f32x2*)&W_hh0[row*16+ 4], wa3 = *(const f32x2*)&W_hh0[row*16+ 6];
    const f32x2 wa4 = *(const f32x2*)&W_hh0[row*16+ 8], wa5 = *(const f32x2*)&W_hh0[row*16+10];
    const f32x2 wa6 = *(const f32x2*)&W_hh0[row*16+12], wa7 = *(const f32x2*)&W_hh0[row*16+14];
    const f32x2 wb0 = *(const f32x2*)&W_ih1[row*16+ 0], wb1 = *(const f32x2*)&W_ih1[row*16+ 2];
    const f32x2 wb2 = *(const f32x2*)&W_ih1[row*16+ 4], wb3 = *(const f32x2*)&W_ih1[row*16+ 6];
    const f32x2 wb4 = *(const f32x2*)&W_ih1[row*16+ 8], wb5 = *(const f32x2*)&W_ih1[row*16+10];
    const f32x2 wb6 = *(const f32x2*)&W_ih1[row*16+12], wb7 = *(const f32x2*)&W_ih1[row*16+14];
    const f32x2 wc0 = *(const f32x2*)&W_hh1[row*16+ 0], wc1 = *(const f32x2*)&W_hh1[row*16+ 2];
    const f32x2 wc2 = *(const f32x2*)&W_hh1[row*16+ 4], wc3 = *(const f32x2*)&W_hh1[row*16+ 6];
    const f32x2 wc4 = *(const f32x2*)&W_hh1[row*16+ 8], wc5 = *(const f32x2*)&W_hh1[row*16+10];
    const f32x2 wc6 = *(const f32x2*)&W_hh1[row*16+12], wc7 = *(const f32x2*)&W_hh1[row*16+14];
    const float wx0 = W_ih0[row];
    const float bb0 = b_ih0[row] + b_hh0[row];
    const float bb1 = b_ih1[row] + b_hh1[row];

    const bool  isT = (g == 2);
    const bool  isF = (g == 1);
    const float Ca  = isT ? (-2.0f * LOG2E) : (-LOG2E);
    const float Aa  = isT ? 2.0f : 1.0f;
    const float Ba  = isT ? -1.0f : 0.0f;
    const float C2P = 2.0f * LOG2E;

    const int wslot = (l & 1) ? (((l & 2) << 3) | j) : (32 + (l >> 1));
    float cs0 = 0.0f, cs1 = 0.0f;

    const f32x2* h0p = (const f32x2*)&lds[0];
    const f32x2* h1p = (const f32x2*)&lds[16];

#define LSTM_STEP(XI, DO_L1)                                                   \
  {                                                                            \
    const f32x2 p0 = h0p[0], p1 = h0p[1], p2 = h0p[2], p3 = h0p[3];            \
    const f32x2 p4 = h0p[4], p5 = h0p[5], p6 = h0p[6], p7 = h0p[7];            \
    const f32x2 s0 = h1p[0], s1 = h1p[1], s2 = h1p[2], s3 = h1p[3];            \
    const f32x2 s4 = h1p[4], s5 = h1p[5], s6 = h1p[6], s7 = h1p[7];            \
    f32x2 a0 = {fmaf((XI), wx0, bb0), 0.0f};                                   \
    f32x2 a1 = {bb1, 0.0f};                                                    \
    a0 = FMA2(wa0, p0, a0); a1 = FMA2(wb0, p0, a1); a1 = FMA2(wc0, s0, a1);    \
    a0 = FMA2(wa1, p1, a0); a1 = FMA2(wb1, p1, a1); a1 = FMA2(wc1, s1, a1);    \
    a0 = FMA2(wa2, p2, a0); a1 = FMA2(wb2, p2, a1); a1 = FMA2(wc2, s2, a1);    \
    a0 = FMA2(wa3, p3, a0); a1 = FMA2(wb3, p3, a1); a1 = FMA2(wc3, s3, a1);    \
    a0 = FMA2(wa4, p4, a0); a1 = FMA2(wb4, p4, a1); a1 = FMA2(wc4, s4, a1);    \
    a0 = FMA2(wa5, p5, a0); a1 = FMA2(wb5, p5, a1); a1 = FMA2(wc5, s5, a1);    \
    a0 = FMA2(wa6, p6, a0); a1 = FMA2(wb6, p6, a1); a1 = FMA2(wc6, s6, a1);    \
    a0 = FMA2(wa7, p7, a0); a1 = FMA2(wb7, p7, a1); a1 = FMA2(wc7, s7, a1);    \
    const float acc0 = a0.x + a0.y;                                            \
    const float acc1 = a1.x + a1.y;                                            \
    const float act0 = fmaf(Aa, fast_rcp(1.0f + fast_exp2(acc0 * Ca)), Ba);    \
    const float act1 = fmaf(Aa, fast_rcp(1.0f + fast_exp2(acc1 * Ca)), Ba);    \
    const float sw0 = dppq<0x4E>(act0);                                        \
    const float sw1 = dppq<0x4E>(act1);                                        \
    const float xp0 = dppq<0xB1>(act0 * sw0);                                  \
    const float xp1 = dppq<0xB1>(act1 * sw1);                                  \
    const float c0n = fmaf(act0, cs0, xp0);                                    \
    const float c1n = fmaf(sw1, cs1, xp1);                                     \
    cs0 = c0n;                                                                 \
    if (DO_L1) cs1 = c1n;                                                      \
    const float tin = isF ? cs0 : cs1;                                         \
    const float e   = fast_exp2(fabsf(tin) * C2P);                             \
    float th = fmaf(-2.0f, fast_rcp(e + 1.0f), 1.0f);                          \
    th = copysignf(th, tin);                                                   \
    const float hv = (isF ? sw0 : act1) * th;                                  \
    lds[wslot] = hv;                                                           \
  }

    // ---- peel t = 0..3 in C++ (t=0 skips the L1 cell update) ----
    {
        float4 xq = *(const float4*)&lds[64];
        LSTM_STEP(xq.x, false)
        LSTM_STEP(xq.y, true)
        LSTM_STEP(xq.z, true)
        LSTM_STEP(xq.w, true)
    }

    // ---- asm loop: t = 4..511 (508 steps), explicit registers ----
    {
        unsigned base  = (unsigned)(size_t)(void*)&lds[0];
        unsigned xad   = base + 256 + 16;       // &lds_x[4]
        unsigned wbyte = base + wslot * 4;
        const float* pwa = W_hh0 + row * 16;
        const float* pwb = W_ih1 + row * 16;
        const float* pwc = W_hh1 + row * 16;
        unsigned long long mF = __ballot(isF);

        asm volatile(
            // ---------- prologue: weights -> v64..v111, addr regs, consts ----------
            "global_load_dwordx4 v[64:67], %[pwa], off\n"
            "global_load_dwordx4 v[68:71], %[pwa], off offset:16\n"
            "global_load_dwordx4 v[72:75], %[pwa], off offset:32\n"
            "global_load_dwordx4 v[76:79], %[pwa], off offset:48\n"
            "global_load_dwordx4 v[80:83], %[pwb], off\n"
            "global_load_dwordx4 v[84:87], %[pwb], off offset:16\n"
            "global_load_dwordx4 v[88:91], %[pwb], off offset:32\n"
            "global_load_dwordx4 v[92:95], %[pwb], off offset:48\n"
            "global_load_dwordx4 v[96:99], %[pwc], off\n"
            "global_load_dwordx4 v[100:103], %[pwc], off offset:16\n"
            "global_load_dwordx4 v[104:107], %[pwc], off offset:32\n"
            "global_load_dwordx4 v[108:111], %[pwc], off offset:48\n"
            "v_mov_b32 v27, %[wbyte]\n"
            "v_mov_b32 v28, %[hb]\n"
            "v_mov_b32 v29, %[xad]\n"
            "s_movk_i32 s22, 508\n"
            "s_mov_b32 s20, 0x7fffffff\n"
            "s_mov_b32 s21, 0x4038aa3b\n"        // 2*log2(e)
            "s_waitcnt vmcnt(0)\n"
            "Llstm_%=:\n"
            // ---------- h + x loads ----------
            "ds_read_b128 v[32:35], v28 offset:0\n"
            "ds_read_b128 v[36:39], v28 offset:16\n"
            "ds_read_b128 v[40:43], v28 offset:32\n"
            "ds_read_b128 v[44:47], v28 offset:48\n"
            "ds_read_b128 v[48:51], v28 offset:64\n"
            "ds_read_b128 v[52:55], v28 offset:80\n"
            "ds_read_b128 v[56:59], v28 offset:96\n"
            "ds_read_b128 v[60:63], v28 offset:112\n"
            "ds_read_b32  v118, v29\n"
            "v_add_u32 v29, 4, v29\n"
            "v_mov_b32 v112, %[bb0]\n"
            "v_mov_b32 v113, 0\n"
            "v_mov_b32 v114, %[bb1]\n"
            "v_mov_b32 v115, 0\n"
            "v_mov_b32 v116, 0\n"
            "v_mov_b32 v117, 0\n"
            "s_waitcnt lgkmcnt(0)\n"
            "v_fmac_f32 v112, v118, %[wx0]\n"
            // ---------- 24 packed FMAs: a0 += wa*h0, a1 += wb*h0, a1b += wc*h1 ----------
            "v_pk_fma_f32 v[112:113], v[64:65], v[32:33], v[112:113]\n"
            "v_pk_fma_f32 v[114:115], v[80:81], v[32:33], v[114:115]\n"
            "v_pk_fma_f32 v[116:117], v[96:97], v[48:49], v[116:117]\n"
            "v_pk_fma_f32 v[112:113], v[66:67], v[34:35], v[112:113]\n"
            "v_pk_fma_f32 v[114:115], v[82:83], v[34:35], v[114:115]\n"
            "v_pk_fma_f32 v[116:117], v[98:99], v[50:51], v[116:117]\n"
            "v_pk_fma_f32 v[112:113], v[68:69], v[36:37], v[112:113]\n"
            "v_pk_fma_f32 v[114:115], v[84:85], v[36:37], v[114:115]\n"
            "v_pk_fma_f32 v[116:117], v[100:101], v[52:53], v[116:117]\n"
            "v_pk_fma_f32 v[112:113], v[70:71], v[38:39], v[112:113]\n"
            "v_pk_fma_f32 v[114:115], v[86:87], v[38:39], v[114:115]\n"
            "v_pk_fma_f32 v[116:117], v[102:103], v[54:55], v[116:117]\n"
            "v_pk_fma_f32 v[112:113], v[72:73], v[40:41], v[112:113]\n"
            "v_pk_fma_f32 v[114:115], v[88:89], v[40:41], v[114:115]\n"
            "v_pk_fma_f32 v[116:117], v[104:105], v[56:57], v[116:117]\n"
            "v_pk_fma_f32 v[112:113], v[74:75], v[42:43], v[112:113]\n"
            "v_pk_fma_f32 v[114:115], v[90:91], v[42:43], v[114:115]\n"
            "v_pk_fma_f32 v[116:117], v[106:107], v[58:59], v[116:117]\n"
            "v_pk_fma_f32 v[112:113], v[76:77], v[44:45], v[112:113]\n"
            "v_pk_fma_f32 v[114:115], v[92:93], v[44:45], v[114:115]\n"
            "v_pk_fma_f32 v[116:117], v[108:109], v[60:61], v[116:117]\n"
            "v_pk_fma_f32 v[112:113], v[78:79], v[46:47], v[112:113]\n"
            "v_pk_fma_f32 v[114:115], v[94:95], v[46:47], v[114:115]\n"
            "v_pk_fma_f32 v[116:117], v[110:111], v[62:63], v[116:117]\n"
            // ---------- horizontal adds ----------
            "v_add_f32 v120, v112, v113\n"
            "v_add_f32 v126, v114, v116\n"
            "v_add_f32 v121, v115, v117\n"
            "v_add_f32 v121, v126, v121\n"
            // ---------- gate activations (interleaved chains) ----------
            "v_mul_f32 v122, %[Ca], v120\n"
            "v_mul_f32 v123, %[Ca], v121\n"
            "v_exp_f32 v122, v122\n"
            "v_exp_f32 v123, v123\n"
            "v_add_f32 v122, 1.0, v122\n"
            "v_add_f32 v123, 1.0, v123\n"
            "v_rcp_f32 v122, v122\n"
            "v_rcp_f32 v123, v123\n"
            "v_fma_f32 v122, %[Aa], v122, %[Ba]\n"
            "v_fma_f32 v123, %[Aa], v123, %[Ba]\n"
            "s_nop 0\n"
            // ---------- cross-gate combine via DPP ----------
            "v_mov_b32_dpp v124, v122 quad_perm:[2,3,0,1] row_mask:0xf bank_mask:0xf\n"
            "v_mov_b32_dpp v125, v123 quad_perm:[2,3,0,1] row_mask:0xf bank_mask:0xf\n"
            "v_mul_f32 v118, v122, v124\n"
            "v_mul_f32 v119, v123, v125\n"
            "s_nop 0\n"
            "v_mov_b32_dpp v118, v118 quad_perm:[1,0,3,2] row_mask:0xf bank_mask:0xf\n"
            "v_mov_b32_dpp v119, v119 quad_perm:[1,0,3,2] row_mask:0xf bank_mask:0xf\n"
            "v_fma_f32 %[cs0], v122, %[cs0], v118\n"
            "v_fma_f32 %[cs1], v125, %[cs1], v119\n"
            // ---------- shared tanh(c) pass + h write ----------
            "v_cndmask_b32 v126, %[cs1], %[cs0], %[mF]\n"
            "v_mul_f32 v127, s21, |v126|\n"
            "v_exp_f32 v127, v127\n"
            "s_nop 0\n"
            "v_add_f32 v127, 1.0, v127\n"
            "v_rcp_f32 v127, v127\n"
            "s_nop 0\n"
            "v_fma_f32 v127, -2.0, v127, 1.0\n"
            "v_bfi_b32 v127, s20, v127, v126\n"
            "v_cndmask_b32 v126, v123, v124, %[mF]\n"
            "v_mul_f32 v126, v126, v127\n"
            "ds_write_b32 v27, v126\n"
            // ---------- loop ----------
            "s_sub_u32 s22, s22, 1\n"
            "s_cmp_lg_u32 s22, 0\n"
            "s_cbranch_scc1 Llstm_%=\n"
            : [cs0]"+v"(cs0), [cs1]"+v"(cs1)
            : [hb]"v"(base), [xad]"v"(xad), [wbyte]"v"(wbyte),
              [pwa]"v"(pwa), [pwb]"v"(pwb), [pwc]"v"(pwc),
              [bb0]"v"(bb0), [bb1]"v"(bb1), [wx0]"v"(wx0),
              [Ca]"v"(Ca), [Aa]"v"(Aa), [Ba]"v"(Ba),
              [mF]"s"(mF)
            : "memory", "scc", "s20", "s21", "s22",
              "v26","v27","v28","v29","v30","v31","v32","v33","v34","v35",
              "v36","v37","v38","v39","v40","v41","v42","v43","v44","v45",
              "v46","v47","v48","v49","v50","v51","v52","v53","v54","v55",
              "v56","v57","v58","v59","v60","v61","v62","v63","v64","v65",
              "v66","v67","v68","v69","v70","v71","v72","v73","v74","v75",
              "v76","v77","v78","v79","v80","v81","v82","v83","v84","v85",
              "v86","v87","v88","v89","v90","v91","v92","v93","v94","v95",
              "v96","v97","v98","v99","v100","v101","v102","v103","v104","v105",
              "v106","v107","v108","v109","v110","v111","v112","v113","v114","v115",
              "v116","v117","v118","v119","v120","v121","v122","v123","v124","v125",
              "v126","v127");
    }

    // ---- final L1 step: consumes h0^{512}, h1^{511} ----
    {
        const f32x2 p0 = h0p[0], p1 = h0p[1], p2 = h0p[2], p3 = h0p[3];
        const f32x2 p4 = h0p[4], p5 = h0p[5], p6 = h0p[6], p7 = h0p[7];
        const f32x2 s0 = h1p[0], s1 = h1p[1], s2 = h1p[2], s3 = h1p[3];
        const f32x2 s4 = h1p[4], s5 = h1p[5], s6 = h1p[6], s7 = h1p[7];
        f32x2 a1 = {bb1, 0.0f};
        a1 = FMA2(wb0, p0, a1); a1 = FMA2(wc0, s0, a1);
        a1 = FMA2(wb1, p1, a1); a1 = FMA2(wc1, s1, a1);
        a1 = FMA2(wb2, p2, a1); a1 = FMA2(wc2, s2, a1);
        a1 = FMA2(wb3, p3, a1); a1 = FMA2(wc3, s3, a1);
        a1 = FMA2(wb4, p4, a1); a1 = FMA2(wc4, s4, a1);
        a1 = FMA2(wb5, p5, a1); a1 = FMA2(wc5, s5, a1);
        a1 = FMA2(wb6, p6, a1); a1 = FMA2(wc6, s6, a1);
        a1 = FMA2(wb7, p7, a1); a1 = FMA2(wc7, s7, a1);
        const float acc1 = a1.x + a1.y;
        const float act1 = fmaf(Aa, fast_rcp(1.0f + fast_exp2(acc1 * Ca)), Ba);
        const float sw1 = dppq<0x4E>(act1);
        const float xp1 = dppq<0xB1>(act1 * sw1);
        cs1 = fmaf(sw1, cs1, xp1);                 // valid on o-lane
        const float e = fast_exp2(fabsf(cs1) * C2P);
        float th = fmaf(-2.0f, fast_rcp(e + 1.0f), 1.0f);
        th = copysignf(th, cs1);
        const float h1fin = act1 * th;             // valid on o-lane

        // FC: out[b] = sum_j h1_j * W_fc[j] + b_fc
        const float wfc = W_fc[j];
        float p = (g == 3) ? h1fin * wfc : 0.0f;
        #pragma unroll
        for (int m = 1; m < 64; m <<= 1) p += __shfl_xor(p, m);
        if (l == 0) out[b] = p + b_fc[0];
    }
#undef LSTM_STEP
}

extern "C" void kernel_launch(void* const* d_in, const int* in_sizes, int n_in,
                              void* d_out, int out_size, void* d_ws, size_t ws_size,
                              hipStream_t stream) {
    const float* x     = (const float*)d_in[0];
    const float* W_ih0 = (const float*)d_in[1];
    const float* W_hh0 = (const float*)d_in[2];
    const float* b_ih0 = (const float*)d_in[3];
    const float* b_hh0 = (const float*)d_in[4];
    const float* W_ih1 = (const float*)d_in[5];
    const float* W_hh1 = (const float*)d_in[6];
    const float* b_ih1 = (const float*)d_in[7];
    const float* b_hh1 = (const float*)d_in[8];
    const float* W_fc  = (const float*)d_in[9];
    const float* b_fc  = (const float*)d_in[10];
    float* out = (float*)d_out;

    dim3 grid(4096), block(64);
    hipLaunchKernelGGL(lstm2_wave, grid, block, 0, stream,
                       x, W_ih0, W_hh0, b_ih0, b_hh0,
                       W_ih1, W_hh1, b_ih1, b_hh1, W_fc, b_fc, out);
}